// Round 5
// baseline (322.472 us; speedup 1.0000x reference)
//
#include <hip/hip_runtime.h>
#include <hip/hip_bf16.h>

typedef __attribute__((ext_vector_type(8))) short bf16x8;
typedef __attribute__((ext_vector_type(4))) float f32x4;
typedef __hip_bfloat16 bf16;
typedef unsigned long long ull;

#define BATCH 8
#define SEQ   2048
#define DMODEL 512
#define DHEAD 64
#define ROWS (BATCH * SEQ)
#define SCALE_LOG2 0.1803368801f   // (1/8) * log2(e)

static __device__ inline short f2bf(float f) {
    union { __hip_bfloat16 h; short s; } u;
    u.h = __float2bfloat16(f);
    return u.s;
}

// ---------------------------------------------------------------------------
// Mask pack: int32 mask -> 1 bit/elem. Chunk = 256 contiguous elems -> 4 ull
// words; word c bit l = mask[chunk*256 + 4*l + c]. 131072 chunks total.
// grid 1024 x 256 (4096 waves x 32 chunks). Coalesced uint4 loads, 4 chunks
// in flight per iteration.
__global__ __launch_bounds__(256) void pack_mask_kernel(
    const int* __restrict__ mask, ull* __restrict__ pm)
{
    const int wgl = (blockIdx.x * 256 + threadIdx.x) >> 6;   // 0..4095
    const int lane = threadIdx.x & 63;
    const uint4* src = (const uint4*)mask;    // index: chunk*64 + lane
    const size_t cbase = (size_t)wgl * 32;

    for (int it = 0; it < 8; ++it) {
        size_t c0 = cbase + it * 4;
        uint4 v0 = src[(c0 + 0) * 64 + lane];
        uint4 v1 = src[(c0 + 1) * 64 + lane];
        uint4 v2 = src[(c0 + 2) * 64 + lane];
        uint4 v3 = src[(c0 + 3) * 64 + lane];
        ull b00 = __ballot(v0.x != 0), b01 = __ballot(v0.y != 0);
        ull b02 = __ballot(v0.z != 0), b03 = __ballot(v0.w != 0);
        ull b10 = __ballot(v1.x != 0), b11 = __ballot(v1.y != 0);
        ull b12 = __ballot(v1.z != 0), b13 = __ballot(v1.w != 0);
        ull b20 = __ballot(v2.x != 0), b21 = __ballot(v2.y != 0);
        ull b22 = __ballot(v2.z != 0), b23 = __ballot(v2.w != 0);
        ull b30 = __ballot(v3.x != 0), b31 = __ballot(v3.y != 0);
        ull b32 = __ballot(v3.z != 0), b33 = __ballot(v3.w != 0);
        if (lane == 0) {
            ull* d = pm + c0 * 4;
            d[0] = b00; d[1] = b01; d[2]  = b02; d[3]  = b03;
            d[4] = b10; d[5] = b11; d[6]  = b12; d[7]  = b13;
            d[8] = b20; d[9] = b21; d[10] = b22; d[11] = b23;
            d[12] = b30; d[13] = b31; d[14] = b32; d[15] = b33;
        }
    }
}

// ---------------------------------------------------------------------------
// W transpose: w[512][64] fp32 -> wt[64][512] bf16. grid 24, block 256.
__global__ __launch_bounds__(256) void transpose_w_kernel(
    const float* __restrict__ wq, const float* __restrict__ wk,
    const float* __restrict__ wv, bf16* __restrict__ wt)
{
    const int s  = blockIdx.x / 8;
    const int kt = blockIdx.x % 8;
    const float* w = (s == 0) ? wq : ((s == 1) ? wk : wv);

    __shared__ float Ts[64][68];

    const int tid = threadIdx.x;
    int nr = tid >> 4;
    int n4 = (tid & 15) * 4;
#pragma unroll
    for (int p = 0; p < 4; ++p) {
        int k = 16 * p + nr;
        float4 v = *(const float4*)(w + (size_t)(kt * 64 + k) * DHEAD + n4);
        Ts[k][n4] = v.x; Ts[k][n4 + 1] = v.y; Ts[k][n4 + 2] = v.z; Ts[k][n4 + 3] = v.w;
    }
    __syncthreads();
#pragma unroll
    for (int p = 0; p < 2; ++p) {
        int cc = tid + p * 256;
        int n = cc >> 3;
        int kk = (cc & 7) * 8;
        bf16x8 o;
#pragma unroll
        for (int e = 0; e < 8; ++e) o[e] = f2bf(Ts[kk + e][n]);
        *(bf16x8*)(wt + (size_t)(s * 64 + n) * DMODEL + kt * 64 + kk) = o;
    }
}

// ---------------------------------------------------------------------------
// Fused QKV projection, XCD-pinned (batch = blockIdx.x & 7). 512 blocks x
// 512 thr (8 waves). Fully-unrolled k-loop, depth-2 x prefetch.
__global__ __launch_bounds__(512, 4) void proj_kernel(
    const float* __restrict__ x, const bf16* __restrict__ wt,
    bf16* __restrict__ Q, bf16* __restrict__ K, bf16* __restrict__ Vt)
{
    const int bb = blockIdx.x & 7;          // batch -> XCD pin
    const int tt = blockIdx.x >> 3;         // 0..63 tile within batch
    const int r0 = bb * SEQ + tt * 32;
    const int tid = threadIdx.x;
    const int lane = tid & 63;
    const int wid = tid >> 6;
    const int strip = wid & 1;
    const int cq = wid >> 1;
    const int l15 = lane & 15;
    const int quad = lane >> 4;

    __shared__ __align__(8) bf16 Vs[64][36];

    f32x4 acc[3] = {};

    const float* xp = x + (size_t)(r0 + 16 * strip + l15) * DMODEL + quad * 8;

    float4 A0[4], A1[4];
    A0[0] = *(const float4*)(xp + 0);  A0[1] = *(const float4*)(xp + 4);
    A0[2] = *(const float4*)(xp + 32); A0[3] = *(const float4*)(xp + 36);
    A1[0] = *(const float4*)(xp + 64); A1[1] = *(const float4*)(xp + 68);
    A1[2] = *(const float4*)(xp + 96); A1[3] = *(const float4*)(xp + 100);

#pragma unroll
    for (int k0 = 0; k0 < DMODEL; k0 += 64) {
        float4* cur = ((k0 >> 6) & 1) ? A1 : A0;
        bf16x8 a0, a1;
        a0[0] = f2bf(cur[0].x); a0[1] = f2bf(cur[0].y); a0[2] = f2bf(cur[0].z); a0[3] = f2bf(cur[0].w);
        a0[4] = f2bf(cur[1].x); a0[5] = f2bf(cur[1].y); a0[6] = f2bf(cur[1].z); a0[7] = f2bf(cur[1].w);
        a1[0] = f2bf(cur[2].x); a1[1] = f2bf(cur[2].y); a1[2] = f2bf(cur[2].z); a1[3] = f2bf(cur[2].w);
        a1[4] = f2bf(cur[3].x); a1[5] = f2bf(cur[3].y); a1[6] = f2bf(cur[3].z); a1[7] = f2bf(cur[3].w);

        if (k0 + 128 < DMODEL) {   // refill 'cur' for k0+128 (values consumed)
            cur[0] = *(const float4*)(xp + k0 + 128);
            cur[1] = *(const float4*)(xp + k0 + 132);
            cur[2] = *(const float4*)(xp + k0 + 160);
            cur[3] = *(const float4*)(xp + k0 + 164);
        }

#pragma unroll
        for (int g = 0; g < 3; ++g) {
            int n = 16 * (3 * cq + g) + l15;
            const bf16* wp = wt + (size_t)n * DMODEL + k0 + quad * 8;
            bf16x8 b0 = *(const bf16x8*)(wp);
            bf16x8 b1 = *(const bf16x8*)(wp + 32);
            acc[g] = __builtin_amdgcn_mfma_f32_16x16x32_bf16(a0, b0, acc[g], 0, 0, 0);
            acc[g] = __builtin_amdgcn_mfma_f32_16x16x32_bf16(a1, b1, acc[g], 0, 0, 0);
        }
    }

#pragma unroll
    for (int g = 0; g < 3; ++g) {
        int ng = 16 * (3 * cq + g) + l15;
        int sel = ng >> 6;
        int col = ng & 63;
#pragma unroll
        for (int r = 0; r < 4; ++r) {
            int rowl = 16 * strip + quad * 4 + r;
            int row = r0 + rowl;
            union { __hip_bfloat16 h; bf16 b; } u;
            u.h = __float2bfloat16(acc[g][r]);
            if (sel == 0)      Q[(size_t)row * DHEAD + col] = u.b;
            else if (sel == 1) K[(size_t)row * DHEAD + col] = u.b;
            else               Vs[col][rowl] = u.b;
        }
    }
    __syncthreads();

    {
        int d = tid >> 3;
        int j4 = (tid & 7) * 4;
        int j0 = tt * 32;
        uint2 payload = *(const uint2*)(&Vs[d][j4]);
        *(uint2*)(Vt + ((size_t)(bb * DHEAD + d)) * SEQ + j0 + j4) = payload;
    }
}

// ---------------------------------------------------------------------------
// Flash attention, packed mask preloaded into registers before the loop:
// zero in-loop mask memory; in-loop traffic is L2-resident K/V only.
// grid (BATCH, SEQ/16), block 256 (4 waves, 4-way j-split).
__global__ __launch_bounds__(256, 4) void flash_kernel(
    const bf16* __restrict__ Q, const bf16* __restrict__ K,
    const bf16* __restrict__ Vt, const ull* __restrict__ pm,
    float* __restrict__ out)
{
    const int b = blockIdx.x;          // batch (XCD-pinned)
    const int q0 = blockIdx.y * 16;
    const int tid = threadIdx.x;
    const int lane = tid & 63;
    const int wid = tid >> 6;          // j-split 0..3
    const int l15 = lane & 15;
    const int quad = lane >> 4;

    __shared__ __align__(16) bf16 Ps[4][16][72];
    __shared__ float Om[4][16][64];
    __shared__ float Lw[4][16];

    // packed mask words for this wave's 512-j range: 2 chunks x 4 rows.
    // word for (r,ch) = pm[(row*8 + wid*2 + ch)*4 + (l15&3)], pre-shifted by
    // l15>>2 so bit (16*s + 4*c) = mask[row][j0 + 16c + l15].
    ull mw[2][4];
    {
        const int sh = l15 >> 2;
#pragma unroll
        for (int ch = 0; ch < 2; ++ch)
#pragma unroll
            for (int r = 0; r < 4; ++r) {
                size_t row = (size_t)(b * SEQ + q0 + quad * 4 + r);
                mw[ch][r] = pm[(row * 8 + wid * 2 + ch) * 4 + (l15 & 3)] >> sh;
            }
    }

    const bf16* qp = Q + ((size_t)(b * SEQ + q0 + l15)) * DHEAD + quad * 8;
    bf16x8 aQ0 = *(const bf16x8*)(qp);
    bf16x8 aQ1 = *(const bf16x8*)(qp + 32);

    f32x4 oacc[4] = {};
    float lsum[4] = {0.f, 0.f, 0.f, 0.f};

    const int jbase = wid * (SEQ / 4);

#pragma unroll
    for (int jt = 0; jt < 8; ++jt) {
        const int ch = jt >> 2;
        const int s = jt & 3;
        const int j0 = jbase + jt * 64;

        // S = Q K^T
        f32x4 sacc[4] = {};
#pragma unroll
        for (int c = 0; c < 4; ++c) {
            const bf16* kp = K + ((size_t)(b * SEQ + j0 + 16 * c + l15)) * DHEAD + quad * 8;
            bf16x8 b0 = *(const bf16x8*)(kp);
            bf16x8 b1 = *(const bf16x8*)(kp + 32);
            sacc[c] = __builtin_amdgcn_mfma_f32_16x16x32_bf16(aQ0, b0, sacc[c], 0, 0, 0);
            sacc[c] = __builtin_amdgcn_mfma_f32_16x16x32_bf16(aQ1, b1, sacc[c], 0, 0, 0);
        }

        // p = maskbit ? exp(s/8) : 0
        float pv[4][4];
#pragma unroll
        for (int c = 0; c < 4; ++c)
#pragma unroll
            for (int r = 0; r < 4; ++r) {
                float e = exp2f(sacc[c][r] * SCALE_LOG2);
                unsigned bit = (unsigned)(mw[ch][r] >> (16 * s + 4 * c)) & 1u;
                float p = bit ? e : 0.0f;
                pv[c][r] = p;
                lsum[r] += p;
            }

        // P: C-layout -> A-layout via wave-private LDS (no barrier)
#pragma unroll
        for (int c = 0; c < 4; ++c)
#pragma unroll
            for (int r = 0; r < 4; ++r) {
                union { __hip_bfloat16 h; bf16 b; } u;
                u.h = __float2bfloat16(pv[c][r]);
                Ps[wid][quad * 4 + r][16 * c + l15] = u.b;
            }

        bf16x8 aP0 = *(const bf16x8*)(&Ps[wid][l15][quad * 8]);
        bf16x8 aP1 = *(const bf16x8*)(&Ps[wid][l15][32 + quad * 8]);
#pragma unroll
        for (int c = 0; c < 4; ++c) {
            const bf16* vp = Vt + ((size_t)b * DHEAD + 16 * c + l15) * SEQ + j0 + quad * 8;
            bf16x8 v0 = *(const bf16x8*)(vp);
            bf16x8 v1 = *(const bf16x8*)(vp + 32);
            oacc[c] = __builtin_amdgcn_mfma_f32_16x16x32_bf16(aP0, v0, oacc[c], 0, 0, 0);
            oacc[c] = __builtin_amdgcn_mfma_f32_16x16x32_bf16(aP1, v1, oacc[c], 0, 0, 0);
        }
    }

#pragma unroll
    for (int r = 0; r < 4; ++r) {
        lsum[r] += __shfl_xor(lsum[r], 1);
        lsum[r] += __shfl_xor(lsum[r], 2);
        lsum[r] += __shfl_xor(lsum[r], 4);
        lsum[r] += __shfl_xor(lsum[r], 8);
    }

#pragma unroll
    for (int c = 0; c < 4; ++c)
#pragma unroll
        for (int r = 0; r < 4; ++r)
            Om[wid][quad * 4 + r][16 * c + l15] = oacc[c][r];
    if (l15 == 0) {
#pragma unroll
        for (int r = 0; r < 4; ++r) Lw[wid][quad * 4 + r] = lsum[r];
    }
    __syncthreads();

    {
        int row = tid >> 4;
        int c0 = (tid & 15) * 4;
        float L = Lw[0][row] + Lw[1][row] + Lw[2][row] + Lw[3][row];
        float invL = 1.0f / L;
        float4 o;
        float* op = (float*)&o;
#pragma unroll
        for (int e = 0; e < 4; ++e) {
            op[e] = (Om[0][row][c0 + e] + Om[1][row][c0 + e] +
                     Om[2][row][c0 + e] + Om[3][row][c0 + e]) * invL;
        }
        *(float4*)(out + ((size_t)(b * SEQ + q0 + row)) * DHEAD + c0) = o;
    }
}

extern "C" void kernel_launch(void* const* d_in, const int* in_sizes, int n_in,
                              void* d_out, int out_size, void* d_ws, size_t ws_size,
                              hipStream_t stream)
{
    // setup_inputs order: mask, x_key_value, wk, wq, wv   (wk BEFORE wq!)
    const int*   mask = (const int*)d_in[0];
    const float* x    = (const float*)d_in[1];
    const float* wk   = (const float*)d_in[2];
    const float* wq   = (const float*)d_in[3];
    const float* wv   = (const float*)d_in[4];
    float* out = (float*)d_out;

    bf16* Qb = (bf16*)d_ws;
    bf16* Kb = Qb + (size_t)ROWS * DHEAD;
    bf16* Vt = Kb + (size_t)ROWS * DHEAD;
    bf16* Wt = Vt + (size_t)BATCH * DHEAD * SEQ;
    ull*  pm = (ull*)(Wt + 3 * 64 * DMODEL);   // byte offset 6488064, 8B-aligned

    pack_mask_kernel<<<dim3(1024), 256, 0, stream>>>(mask, pm);
    transpose_w_kernel<<<dim3(24), 256, 0, stream>>>(wq, wk, wv, Wt);
    proj_kernel<<<dim3(ROWS / 32), 512, 0, stream>>>(x, Wt, Qb, Kb, Vt);
    flash_kernel<<<dim3(BATCH, SEQ / 16), 256, 0, stream>>>(Qb, Kb, Vt, pm, out);
}

// Round 6
// 313.306 us; speedup vs baseline: 1.0293x; 1.0293x over previous
//
#include <hip/hip_runtime.h>
#include <hip/hip_bf16.h>

typedef __attribute__((ext_vector_type(8))) short bf16x8;
typedef __attribute__((ext_vector_type(4))) float f32x4;
typedef __hip_bfloat16 bf16;
typedef unsigned long long ull;

#define BATCH 8
#define SEQ   2048
#define DMODEL 512
#define DHEAD 64
#define ROWS (BATCH * SEQ)
#define SCALE_LOG2 0.1803368801f   // (1/8) * log2(e)

static __device__ inline short f2bf(float f) {
    union { __hip_bfloat16 h; short s; } u;
    u.h = __float2bfloat16(f);
    return u.s;
}

// ---------------------------------------------------------------------------
// Mask pack: int32 mask -> 1 bit/elem. Chunk = 256 contiguous elems -> 4 ull
// words; word c bit l = mask[chunk*256 + 4*l + c]. 131072 chunks.
// grid 2048 x 256 (8192 waves x 16 chunks, 4 iters x 4 chunks in flight).
__global__ __launch_bounds__(256) void pack_mask_kernel(
    const int* __restrict__ mask, ull* __restrict__ pm)
{
    const int wgl = (blockIdx.x * 256 + threadIdx.x) >> 6;   // 0..8191
    const int lane = threadIdx.x & 63;
    const uint4* src = (const uint4*)mask;    // index: chunk*64 + lane
    const size_t cbase = (size_t)wgl * 16;

    for (int it = 0; it < 4; ++it) {
        size_t c0 = cbase + it * 4;
        uint4 v0 = src[(c0 + 0) * 64 + lane];
        uint4 v1 = src[(c0 + 1) * 64 + lane];
        uint4 v2 = src[(c0 + 2) * 64 + lane];
        uint4 v3 = src[(c0 + 3) * 64 + lane];
        ull b00 = __ballot(v0.x != 0), b01 = __ballot(v0.y != 0);
        ull b02 = __ballot(v0.z != 0), b03 = __ballot(v0.w != 0);
        ull b10 = __ballot(v1.x != 0), b11 = __ballot(v1.y != 0);
        ull b12 = __ballot(v1.z != 0), b13 = __ballot(v1.w != 0);
        ull b20 = __ballot(v2.x != 0), b21 = __ballot(v2.y != 0);
        ull b22 = __ballot(v2.z != 0), b23 = __ballot(v2.w != 0);
        ull b30 = __ballot(v3.x != 0), b31 = __ballot(v3.y != 0);
        ull b32 = __ballot(v3.z != 0), b33 = __ballot(v3.w != 0);
        if (lane == 0) {
            ull* d = pm + c0 * 4;
            d[0] = b00; d[1] = b01; d[2]  = b02; d[3]  = b03;
            d[4] = b10; d[5] = b11; d[6]  = b12; d[7]  = b13;
            d[8] = b20; d[9] = b21; d[10] = b22; d[11] = b23;
            d[12] = b30; d[13] = b31; d[14] = b32; d[15] = b33;
        }
    }
}

// ---------------------------------------------------------------------------
// W transpose: w[512][64] fp32 -> wt[64][512] bf16. grid 24, block 256.
__global__ __launch_bounds__(256) void transpose_w_kernel(
    const float* __restrict__ wq, const float* __restrict__ wk,
    const float* __restrict__ wv, bf16* __restrict__ wt)
{
    const int s  = blockIdx.x / 8;
    const int kt = blockIdx.x % 8;
    const float* w = (s == 0) ? wq : ((s == 1) ? wk : wv);

    __shared__ float Ts[64][68];

    const int tid = threadIdx.x;
    int nr = tid >> 4;
    int n4 = (tid & 15) * 4;
#pragma unroll
    for (int p = 0; p < 4; ++p) {
        int k = 16 * p + nr;
        float4 v = *(const float4*)(w + (size_t)(kt * 64 + k) * DHEAD + n4);
        Ts[k][n4] = v.x; Ts[k][n4 + 1] = v.y; Ts[k][n4 + 2] = v.z; Ts[k][n4 + 3] = v.w;
    }
    __syncthreads();
#pragma unroll
    for (int p = 0; p < 2; ++p) {
        int cc = tid + p * 256;
        int n = cc >> 3;
        int kk = (cc & 7) * 8;
        bf16x8 o;
#pragma unroll
        for (int e = 0; e < 8; ++e) o[e] = f2bf(Ts[kk + e][n]);
        *(bf16x8*)(wt + (size_t)(s * 64 + n) * DMODEL + kt * 64 + kk) = o;
    }
}

// ---------------------------------------------------------------------------
// Fused QKV projection. grid 1024 (XCD-pinned: batch = bid&7), block 256
// (4 waves). All waves share the block's 16 x-rows (L1 reuse); wave cq owns
// 3 of the 12 col-groups. No manual prefetch, no private arrays — the fully
// unrolled k-loop lets the compiler pipeline in registers.
__global__ __launch_bounds__(256) void proj_kernel(
    const float* __restrict__ x, const bf16* __restrict__ wt,
    bf16* __restrict__ Q, bf16* __restrict__ K, bf16* __restrict__ Vt)
{
    const int bb = blockIdx.x & 7;          // batch -> XCD pin
    const int tt = blockIdx.x >> 3;         // 0..127 tile within batch
    const int r0 = bb * SEQ + tt * 16;
    const int tid = threadIdx.x;
    const int lane = tid & 63;
    const int cq = tid >> 6;                // 0..3 col quarter
    const int l15 = lane & 15;
    const int quad = lane >> 4;

    __shared__ __align__(8) bf16 Vs[64][20];   // padded: conflict-free

    f32x4 acc[3] = {};

    const float* xp = x + (size_t)(r0 + l15) * DMODEL + quad * 8;

#pragma unroll
    for (int k0 = 0; k0 < DMODEL; k0 += 64) {
        float4 xa = *(const float4*)(xp + k0);
        float4 xb = *(const float4*)(xp + k0 + 4);
        float4 xc = *(const float4*)(xp + k0 + 32);
        float4 xd = *(const float4*)(xp + k0 + 36);
        bf16x8 a0, a1;
        a0[0] = f2bf(xa.x); a0[1] = f2bf(xa.y); a0[2] = f2bf(xa.z); a0[3] = f2bf(xa.w);
        a0[4] = f2bf(xb.x); a0[5] = f2bf(xb.y); a0[6] = f2bf(xb.z); a0[7] = f2bf(xb.w);
        a1[0] = f2bf(xc.x); a1[1] = f2bf(xc.y); a1[2] = f2bf(xc.z); a1[3] = f2bf(xc.w);
        a1[4] = f2bf(xd.x); a1[5] = f2bf(xd.y); a1[6] = f2bf(xd.z); a1[7] = f2bf(xd.w);

#pragma unroll
        for (int g = 0; g < 3; ++g) {
            int n = 16 * (3 * cq + g) + l15;
            const bf16* wp = wt + (size_t)n * DMODEL + k0 + quad * 8;
            bf16x8 b0 = *(const bf16x8*)(wp);
            bf16x8 b1 = *(const bf16x8*)(wp + 32);
            acc[g] = __builtin_amdgcn_mfma_f32_16x16x32_bf16(a0, b0, acc[g], 0, 0, 0);
            acc[g] = __builtin_amdgcn_mfma_f32_16x16x32_bf16(a1, b1, acc[g], 0, 0, 0);
        }
    }

#pragma unroll
    for (int g = 0; g < 3; ++g) {
        int ng = 16 * (3 * cq + g) + l15;   // 0..191
        int sel = ng >> 6;
        int col = ng & 63;
#pragma unroll
        for (int r = 0; r < 4; ++r) {
            int rowl = quad * 4 + r;            // 0..15
            int row = r0 + rowl;
            union { __hip_bfloat16 h; bf16 b; } u;
            u.h = __float2bfloat16(acc[g][r]);
            if (sel == 0)      Q[(size_t)row * DHEAD + col] = u.b;
            else if (sel == 1) K[(size_t)row * DHEAD + col] = u.b;
            else               Vs[col][rowl] = u.b;
        }
    }
    __syncthreads();

    {   // coalesced Vt store: 256 thr x 8B = 64 d-rows x 16 j
        int d = tid >> 2;
        int j4 = (tid & 3) * 4;
        uint2 payload = *(const uint2*)(&Vs[d][j4]);
        *(uint2*)(Vt + ((size_t)(bb * DHEAD + d)) * SEQ + tt * 16 + j4) = payload;
    }
}

// ---------------------------------------------------------------------------
// Flash attention. Packed mask words loaded per-iteration as SSA scalars
// (4 dword-class loads/iter from L2-resident pm) — no register arrays, no
// scratch. grid (BATCH, SEQ/16), block 256 (4 waves, 4-way j-split), zero
// in-loop barriers.
__global__ __launch_bounds__(256) void flash_kernel(
    const bf16* __restrict__ Q, const bf16* __restrict__ K,
    const bf16* __restrict__ Vt, const ull* __restrict__ pm,
    float* __restrict__ out)
{
    const int b = blockIdx.x;          // batch (XCD-pinned)
    const int q0 = blockIdx.y * 16;
    const int tid = threadIdx.x;
    const int lane = tid & 63;
    const int wid = tid >> 6;          // j-split 0..3
    const int l15 = lane & 15;
    const int quad = lane >> 4;

    __shared__ __align__(16) bf16 Ps[4][16][72];
    __shared__ float Om[4][16][64];
    __shared__ float Lw[4][16];

    // per-row packed-mask pointers: word for (r, ch) = pr[ch*4];
    // bit (16*s + 4*c) after >> (l15>>2) = mask[row][jbase + 64*jt + 16c + l15]
    const int sh = l15 >> 2;
    const ull* p0 = pm + ((size_t)(b * SEQ + q0 + quad * 4 + 0) * 8 + wid * 2) * 4 + (l15 & 3);
    const ull* p1 = pm + ((size_t)(b * SEQ + q0 + quad * 4 + 1) * 8 + wid * 2) * 4 + (l15 & 3);
    const ull* p2 = pm + ((size_t)(b * SEQ + q0 + quad * 4 + 2) * 8 + wid * 2) * 4 + (l15 & 3);
    const ull* p3 = pm + ((size_t)(b * SEQ + q0 + quad * 4 + 3) * 8 + wid * 2) * 4 + (l15 & 3);

    const bf16* qp = Q + ((size_t)(b * SEQ + q0 + l15)) * DHEAD + quad * 8;
    bf16x8 aQ0 = *(const bf16x8*)(qp);
    bf16x8 aQ1 = *(const bf16x8*)(qp + 32);

    f32x4 oacc[4] = {};
    float lsum[4] = {0.f, 0.f, 0.f, 0.f};

    const int jbase = wid * (SEQ / 4);

#pragma unroll
    for (int jt = 0; jt < 8; ++jt) {
        const int ch = jt >> 2;
        const int s = jt & 3;
        const int j0 = jbase + jt * 64;

        // mask words for this tile (SSA scalars; L2-resident, 4 tiny loads)
        ull w0 = p0[ch * 4] >> sh;
        ull w1 = p1[ch * 4] >> sh;
        ull w2 = p2[ch * 4] >> sh;
        ull w3 = p3[ch * 4] >> sh;

        // S = Q K^T
        f32x4 sacc[4] = {};
#pragma unroll
        for (int c = 0; c < 4; ++c) {
            const bf16* kp = K + ((size_t)(b * SEQ + j0 + 16 * c + l15)) * DHEAD + quad * 8;
            bf16x8 b0 = *(const bf16x8*)(kp);
            bf16x8 b1 = *(const bf16x8*)(kp + 32);
            sacc[c] = __builtin_amdgcn_mfma_f32_16x16x32_bf16(aQ0, b0, sacc[c], 0, 0, 0);
            sacc[c] = __builtin_amdgcn_mfma_f32_16x16x32_bf16(aQ1, b1, sacc[c], 0, 0, 0);
        }

        // p = maskbit ? exp(s/8) : 0, store to wave-private Ps (no barrier)
#pragma unroll
        for (int c = 0; c < 4; ++c) {
            {
                float e = exp2f(sacc[c][0] * SCALE_LOG2);
                float p = ((w0 >> (16 * s + 4 * c)) & 1ull) ? e : 0.0f;
                lsum[0] += p;
                union { __hip_bfloat16 h; bf16 b; } u; u.h = __float2bfloat16(p);
                Ps[wid][quad * 4 + 0][16 * c + l15] = u.b;
            }
            {
                float e = exp2f(sacc[c][1] * SCALE_LOG2);
                float p = ((w1 >> (16 * s + 4 * c)) & 1ull) ? e : 0.0f;
                lsum[1] += p;
                union { __hip_bfloat16 h; bf16 b; } u; u.h = __float2bfloat16(p);
                Ps[wid][quad * 4 + 1][16 * c + l15] = u.b;
            }
            {
                float e = exp2f(sacc[c][2] * SCALE_LOG2);
                float p = ((w2 >> (16 * s + 4 * c)) & 1ull) ? e : 0.0f;
                lsum[2] += p;
                union { __hip_bfloat16 h; bf16 b; } u; u.h = __float2bfloat16(p);
                Ps[wid][quad * 4 + 2][16 * c + l15] = u.b;
            }
            {
                float e = exp2f(sacc[c][3] * SCALE_LOG2);
                float p = ((w3 >> (16 * s + 4 * c)) & 1ull) ? e : 0.0f;
                lsum[3] += p;
                union { __hip_bfloat16 h; bf16 b; } u; u.h = __float2bfloat16(p);
                Ps[wid][quad * 4 + 3][16 * c + l15] = u.b;
            }
        }

        bf16x8 aP0 = *(const bf16x8*)(&Ps[wid][l15][quad * 8]);
        bf16x8 aP1 = *(const bf16x8*)(&Ps[wid][l15][32 + quad * 8]);
#pragma unroll
        for (int c = 0; c < 4; ++c) {
            const bf16* vp = Vt + ((size_t)b * DHEAD + 16 * c + l15) * SEQ + j0 + quad * 8;
            bf16x8 v0 = *(const bf16x8*)(vp);
            bf16x8 v1 = *(const bf16x8*)(vp + 32);
            oacc[c] = __builtin_amdgcn_mfma_f32_16x16x32_bf16(aP0, v0, oacc[c], 0, 0, 0);
            oacc[c] = __builtin_amdgcn_mfma_f32_16x16x32_bf16(aP1, v1, oacc[c], 0, 0, 0);
        }
    }

#pragma unroll
    for (int r = 0; r < 4; ++r) {
        lsum[r] += __shfl_xor(lsum[r], 1);
        lsum[r] += __shfl_xor(lsum[r], 2);
        lsum[r] += __shfl_xor(lsum[r], 4);
        lsum[r] += __shfl_xor(lsum[r], 8);
    }

#pragma unroll
    for (int c = 0; c < 4; ++c)
#pragma unroll
        for (int r = 0; r < 4; ++r)
            Om[wid][quad * 4 + r][16 * c + l15] = oacc[c][r];
    if (l15 == 0) {
#pragma unroll
        for (int r = 0; r < 4; ++r) Lw[wid][quad * 4 + r] = lsum[r];
    }
    __syncthreads();

    {
        int row = tid >> 4;
        int c0 = (tid & 15) * 4;
        float L = Lw[0][row] + Lw[1][row] + Lw[2][row] + Lw[3][row];
        float invL = 1.0f / L;
        float4 o;
        float* op = (float*)&o;
#pragma unroll
        for (int e = 0; e < 4; ++e) {
            op[e] = (Om[0][row][c0 + e] + Om[1][row][c0 + e] +
                     Om[2][row][c0 + e] + Om[3][row][c0 + e]) * invL;
        }
        *(float4*)(out + ((size_t)(b * SEQ + q0 + row)) * DHEAD + c0) = o;
    }
}

extern "C" void kernel_launch(void* const* d_in, const int* in_sizes, int n_in,
                              void* d_out, int out_size, void* d_ws, size_t ws_size,
                              hipStream_t stream)
{
    // setup_inputs order: mask, x_key_value, wk, wq, wv   (wk BEFORE wq!)
    const int*   mask = (const int*)d_in[0];
    const float* x    = (const float*)d_in[1];
    const float* wk   = (const float*)d_in[2];
    const float* wq   = (const float*)d_in[3];
    const float* wv   = (const float*)d_in[4];
    float* out = (float*)d_out;

    bf16* Qb = (bf16*)d_ws;
    bf16* Kb = Qb + (size_t)ROWS * DHEAD;
    bf16* Vt = Kb + (size_t)ROWS * DHEAD;
    bf16* Wt = Vt + (size_t)BATCH * DHEAD * SEQ;
    ull*  pm = (ull*)(Wt + 3 * 64 * DMODEL);   // 8B-aligned

    pack_mask_kernel<<<dim3(2048), 256, 0, stream>>>(mask, pm);
    transpose_w_kernel<<<dim3(24), 256, 0, stream>>>(wq, wk, wv, Wt);
    proj_kernel<<<dim3(1024), 256, 0, stream>>>(x, Wt, Qb, Kb, Vt);
    flash_kernel<<<dim3(BATCH, SEQ / 16), 256, 0, stream>>>(Qb, Kb, Vt, pm, out);
}